// Round 1
// baseline (1144.115 us; speedup 1.0000x reference)
//
#include <hip/hip_runtime.h>
#include <hip/hip_bf16.h>
#include <math.h>

#define TOK 8192       // B*S
#define DIM 256
#define SEQ 1024
#define NH 8
#define DHD 32
#define FFD 1024
#define NL 2
#define VOCAB 32000

// ---------------- embedding + ngram + tfidf bias ----------------
__global__ __launch_bounds__(256) void embed_kernel(
    const int* __restrict__ ids, const int* __restrict__ ngram_ids,
    const float* __restrict__ tfidf, const float* __restrict__ emb,
    const float* __restrict__ pos, const float* __restrict__ bucket,
    float* __restrict__ x, float* __restrict__ bias_base)
{
  __shared__ int ngs[12];
  const int t = blockIdx.x;
  const int id = ids[t];
  int idc = id; if (idc < 0) idc = 0; if (idc > VOCAB-1) idc = VOCAB-1;
  if (threadIdx.x < 12) ngs[threadIdx.x] = ngram_ids[idc*12 + threadIdx.x];
  if (threadIdx.x == 0) bias_base[t] = tfidf[idc];
  __syncthreads();
  const int d = threadIdx.x;
  const int s = t & (SEQ - 1);
  float v = emb[(size_t)id*DIM + d] + pos[s*DIM + d];
  float sum = 0.f; int cnt = 0;
  #pragma unroll
  for (int g = 0; g < 12; ++g) {
    const int ng = ngs[g];
    if (ng != 0) { sum += bucket[(size_t)ng*DIM + d]; cnt++; }
  }
  v += sum / fmaxf((float)cnt, 1.0f);
  x[(size_t)t*DIM + d] = v;
}

// ---------------- layernorm: 1 wave per row, 4 rows/block ----------------
__global__ __launch_bounds__(256) void ln_kernel(
    const float* __restrict__ x, const float* __restrict__ g,
    const float* __restrict__ b, float* __restrict__ y)
{
  const int wave = threadIdx.x >> 6, lane = threadIdx.x & 63;
  const int row = blockIdx.x * 4 + wave;
  const float* xr = x + (size_t)row * DIM;
  float4 v = *reinterpret_cast<const float4*>(xr + lane*4);
  float s = v.x + v.y + v.z + v.w;
  #pragma unroll
  for (int o = 32; o >= 1; o >>= 1) s += __shfl_xor(s, o);
  const float mean = s * (1.f/256.f);
  const float dx0 = v.x-mean, dx1 = v.y-mean, dx2 = v.z-mean, dx3 = v.w-mean;
  float q = dx0*dx0 + dx1*dx1 + dx2*dx2 + dx3*dx3;
  #pragma unroll
  for (int o = 32; o >= 1; o >>= 1) q += __shfl_xor(q, o);
  const float rs = rsqrtf(q * (1.f/256.f) + 1e-5f);
  float4 gv = *reinterpret_cast<const float4*>(g + lane*4);
  float4 bv = *reinterpret_cast<const float4*>(b + lane*4);
  float4 o4;
  o4.x = dx0*rs*gv.x + bv.x;
  o4.y = dx1*rs*gv.y + bv.y;
  o4.z = dx2*rs*gv.z + bv.z;
  o4.w = dx3*rs*gv.w + bv.w;
  *reinterpret_cast<float4*>(y + (size_t)row*DIM + lane*4) = o4;
}

// ---------------- fp32 GEMM: C[M,N] = A[M,K] @ W[K,N] + bias ----------------
// 64x64 tile, BK=16, 256 threads, 4x4 per thread.
template<bool RELU, bool ACC>
__global__ __launch_bounds__(256) void gemm_f32(
    const float* __restrict__ A, const float* __restrict__ W,
    const float* __restrict__ bias, float* __restrict__ C,
    int M, int N, int K)
{
  __shared__ float As[16][68];   // [k][m], padded to 68 (float4-aligned, bank-spread)
  __shared__ float Bs[16][64];   // [k][n]
  const int bm = blockIdx.y * 64, bn = blockIdx.x * 64;
  const int tid = threadIdx.x;
  const int ty = tid >> 4, tx = tid & 15;
  const int arow = tid >> 2, ak4 = (tid & 3) << 2;
  const int bkr = tid >> 4, bn4 = (tid & 15) << 2;
  float acc[4][4] = {};
  for (int k0 = 0; k0 < K; k0 += 16) {
    const float4 av = *reinterpret_cast<const float4*>(&A[(size_t)(bm+arow)*K + k0 + ak4]);
    const float4 bv = *reinterpret_cast<const float4*>(&W[(size_t)(k0+bkr)*N + bn + bn4]);
    As[ak4+0][arow] = av.x; As[ak4+1][arow] = av.y;
    As[ak4+2][arow] = av.z; As[ak4+3][arow] = av.w;
    *reinterpret_cast<float4*>(&Bs[bkr][bn4]) = bv;
    __syncthreads();
    #pragma unroll
    for (int kk = 0; kk < 16; ++kk) {
      const float4 a4 = *reinterpret_cast<const float4*>(&As[kk][ty << 2]);
      const float4 b4 = *reinterpret_cast<const float4*>(&Bs[kk][tx << 2]);
      const float a[4]  = {a4.x, a4.y, a4.z, a4.w};
      const float bb[4] = {b4.x, b4.y, b4.z, b4.w};
      #pragma unroll
      for (int i = 0; i < 4; ++i)
        #pragma unroll
        for (int j = 0; j < 4; ++j)
          acc[i][j] += a[i] * bb[j];
    }
    __syncthreads();
  }
  #pragma unroll
  for (int i = 0; i < 4; ++i) {
    const int row = bm + (ty << 2) + i;
    #pragma unroll
    for (int j = 0; j < 4; ++j) {
      const int col = bn + (tx << 2) + j;
      float vv = acc[i][j] + bias[col];
      if (RELU) vv = fmaxf(vv, 0.f);
      const size_t idx = (size_t)row * N + col;
      if (ACC) C[idx] += vv; else C[idx] = vv;
    }
  }
}

// ---------------- flash attention, fp32 ----------------
// block = 256 threads; handles (b, h, 64 q-rows). 4 threads per q-row.
__global__ __launch_bounds__(256) void attn_kernel(
    const float* __restrict__ Q, const float* __restrict__ K,
    const float* __restrict__ V, const float* __restrict__ bias_base,
    const int* __restrict__ ids, const float* __restrict__ alpha_arr, int l,
    float* __restrict__ O)
{
  const int qb = blockIdx.x * 64;
  const int h  = blockIdx.y;
  const int b  = blockIdx.z;
  const float alpha = alpha_arr[l];
  const float scale = 0.17677669529663687f;  // 1/sqrt(32)
  __shared__ float Ks[64][36];
  __shared__ float Vs[64][36];
  __shared__ float Ps[64][68];
  __shared__ float bias_s[64];
  const int tid = threadIdx.x;
  const int r  = tid >> 2;    // q row within block
  const int qt = tid & 3;     // quarter: owns dims qt*8..qt*8+7 and keys qt*16..qt*16+15
  // q row -> registers (4 threads/row, redundant)
  float qreg[32];
  {
    const float* qp = Q + (size_t)(b*SEQ + qb + r)*DIM + h*DHD;
    #pragma unroll
    for (int i = 0; i < 8; ++i) {
      const float4 t4 = *reinterpret_cast<const float4*>(qp + i*4);
      qreg[i*4+0]=t4.x; qreg[i*4+1]=t4.y; qreg[i*4+2]=t4.z; qreg[i*4+3]=t4.w;
    }
  }
  float m_run = -1e30f, l_run = 0.f;
  float acc[8] = {0,0,0,0,0,0,0,0};
  const int li = tid >> 2, d8 = (tid & 3) * 8;
  for (int kt = 0; kt < SEQ; kt += 64) {
    // stage K,V tile
    const float* kp = K + (size_t)(b*SEQ + kt + li)*DIM + h*DHD + d8;
    const float* vp = V + (size_t)(b*SEQ + kt + li)*DIM + h*DHD + d8;
    const float4 ka = *reinterpret_cast<const float4*>(kp);
    const float4 kb = *reinterpret_cast<const float4*>(kp + 4);
    const float4 va = *reinterpret_cast<const float4*>(vp);
    const float4 vb = *reinterpret_cast<const float4*>(vp + 4);
    *reinterpret_cast<float4*>(&Ks[li][d8])     = ka;
    *reinterpret_cast<float4*>(&Ks[li][d8 + 4]) = kb;
    *reinterpret_cast<float4*>(&Vs[li][d8])     = va;
    *reinterpret_cast<float4*>(&Vs[li][d8 + 4]) = vb;
    if (tid < 64) {
      const int spos = b*SEQ + kt + tid;
      const int kid = ids[spos];
      bias_s[tid] = (kid == 0) ? -1e30f : bias_base[spos] * alpha;
    }
    __syncthreads();
    // scores for 16 keys
    float p[16];
    float tmax = -1e30f;
    #pragma unroll
    for (int jj = 0; jj < 16; ++jj) {
      const int j = (qt << 4) + jj;
      float sacc = 0.f;
      #pragma unroll
      for (int d4 = 0; d4 < 8; ++d4) {
        const float4 k4 = *reinterpret_cast<const float4*>(&Ks[j][d4*4]);
        sacc += qreg[d4*4+0]*k4.x + qreg[d4*4+1]*k4.y + qreg[d4*4+2]*k4.z + qreg[d4*4+3]*k4.w;
      }
      sacc = sacc*scale + bias_s[j];
      p[jj] = sacc;
      tmax = fmaxf(tmax, sacc);
    }
    tmax = fmaxf(tmax, __shfl_xor(tmax, 1));
    tmax = fmaxf(tmax, __shfl_xor(tmax, 2));
    const float m_new = fmaxf(m_run, tmax);
    const float sc_old = __expf(m_run - m_new);
    float lsum = 0.f;
    #pragma unroll
    for (int jj = 0; jj < 16; ++jj) {
      const float e = __expf(p[jj] - m_new);
      Ps[r][(qt << 4) + jj] = e;
      lsum += e;
    }
    lsum += __shfl_xor(lsum, 1);
    lsum += __shfl_xor(lsum, 2);
    l_run = l_run * sc_old + lsum;
    #pragma unroll
    for (int dd = 0; dd < 8; ++dd) acc[dd] *= sc_old;
    __syncthreads();   // Ps visible (same wave in fact, but keep it safe)
    #pragma unroll
    for (int j = 0; j < 64; ++j) {
      const float pv = Ps[r][j];
      const float4 v0 = *reinterpret_cast<const float4*>(&Vs[j][qt*8]);
      const float4 v1 = *reinterpret_cast<const float4*>(&Vs[j][qt*8 + 4]);
      acc[0] += pv*v0.x; acc[1] += pv*v0.y; acc[2] += pv*v0.z; acc[3] += pv*v0.w;
      acc[4] += pv*v1.x; acc[5] += pv*v1.y; acc[6] += pv*v1.z; acc[7] += pv*v1.w;
    }
    m_run = m_new;
    __syncthreads();
  }
  const float inv = 1.f / l_run;
  float* op = O + (size_t)(b*SEQ + qb + r)*DIM + h*DHD + qt*8;
  #pragma unroll
  for (int dd = 0; dd < 8; ++dd) op[dd] = acc[dd] * inv;
}

// ---------------- final LN (row 0 per batch) + classifier ----------------
__global__ __launch_bounds__(256) void cls_kernel(
    const float* __restrict__ x, const float* __restrict__ gf,
    const float* __restrict__ bf, const float* __restrict__ Wc,
    const float* __restrict__ bc, float* __restrict__ out)
{
  const int b = blockIdx.x;
  const int tid = threadIdx.x;
  const int wave = tid >> 6, lane = tid & 63;
  const float* xr = x + (size_t)b * SEQ * DIM;   // row (b, s=0)
  const float v = xr[tid];
  __shared__ float redm[4], redv[4], redc[4][4];
  float s = v;
  #pragma unroll
  for (int o = 32; o >= 1; o >>= 1) s += __shfl_xor(s, o);
  if (lane == 0) redm[wave] = s;
  __syncthreads();
  const float mean = (redm[0]+redm[1]+redm[2]+redm[3]) * (1.f/256.f);
  const float dv = v - mean;
  float q = dv * dv;
  #pragma unroll
  for (int o = 32; o >= 1; o >>= 1) q += __shfl_xor(q, o);
  if (lane == 0) redv[wave] = q;
  __syncthreads();
  const float var = (redv[0]+redv[1]+redv[2]+redv[3]) * (1.f/256.f);
  const float rs = rsqrtf(var + 1e-5f);
  const float yn = dv*rs*gf[tid] + bf[tid];
  float pc[4];
  #pragma unroll
  for (int c = 0; c < 4; ++c) pc[c] = yn * Wc[tid*4 + c];
  #pragma unroll
  for (int c = 0; c < 4; ++c) {
    #pragma unroll
    for (int o = 32; o >= 1; o >>= 1) pc[c] += __shfl_xor(pc[c], o);
  }
  if (lane == 0) {
    #pragma unroll
    for (int c = 0; c < 4; ++c) redc[wave][c] = pc[c];
  }
  __syncthreads();
  if (tid < 4) {
    out[b*4 + tid] = redc[0][tid] + redc[1][tid] + redc[2][tid] + redc[3][tid] + bc[tid];
  }
}

extern "C" void kernel_launch(void* const* d_in, const int* in_sizes, int n_in,
                              void* d_out, int out_size, void* d_ws, size_t ws_size,
                              hipStream_t stream)
{
  const int*   ids    = (const int*)d_in[0];
  const int*   ngrams = (const int*)d_in[1];
  const float* tfidf  = (const float*)d_in[2];
  const float* emb    = (const float*)d_in[3];
  const float* pos    = (const float*)d_in[4];
  const float* bucket = (const float*)d_in[5];
  const float* Wq = (const float*)d_in[6];  const float* bq = (const float*)d_in[7];
  const float* Wk = (const float*)d_in[8];  const float* bk = (const float*)d_in[9];
  const float* Wv = (const float*)d_in[10]; const float* bv = (const float*)d_in[11];
  const float* Wo = (const float*)d_in[12]; const float* bo = (const float*)d_in[13];
  const float* g1 = (const float*)d_in[14]; const float* be1= (const float*)d_in[15];
  const float* g2 = (const float*)d_in[16]; const float* be2= (const float*)d_in[17];
  const float* W1 = (const float*)d_in[18]; const float* b1 = (const float*)d_in[19];
  const float* W2 = (const float*)d_in[20]; const float* b2 = (const float*)d_in[21];
  const float* alpha = (const float*)d_in[22];
  const float* gf = (const float*)d_in[23]; const float* bf = (const float*)d_in[24];
  const float* Wc = (const float*)d_in[25]; const float* bc = (const float*)d_in[26];

  float* ws = (float*)d_ws;
  float* x    = ws;                    // 2,097,152 f
  float* x2   = ws + 2097152;          // 2,097,152 f
  float* q    = ws + 4194304;
  float* k    = ws + 6291456;
  float* v    = ws + 8388608;
  float* att  = ws + 10485760;
  float* mid  = ws + 4194304;          // reuses q/k/v/att range (dead during FFN)
  float* bias_base = ws + 12582912;    // 8192 f  -> total ~50.4 MB

  embed_kernel<<<TOK, 256, 0, stream>>>(ids, ngrams, tfidf, emb, pos, bucket, x, bias_base);

  const dim3 g64(DIM/64, TOK/64);
  const dim3 gff(FFD/64, TOK/64);
  const dim3 ga(SEQ/64, NH, 8);
  for (int l = 0; l < NL; ++l) {
    ln_kernel<<<TOK/4, 256, 0, stream>>>(x, g1 + l*DIM, be1 + l*DIM, x2);
    gemm_f32<false,false><<<g64, 256, 0, stream>>>(x2, Wq + (size_t)l*DIM*DIM, bq + l*DIM, q, TOK, DIM, DIM);
    gemm_f32<false,false><<<g64, 256, 0, stream>>>(x2, Wk + (size_t)l*DIM*DIM, bk + l*DIM, k, TOK, DIM, DIM);
    gemm_f32<false,false><<<g64, 256, 0, stream>>>(x2, Wv + (size_t)l*DIM*DIM, bv + l*DIM, v, TOK, DIM, DIM);
    attn_kernel<<<ga, 256, 0, stream>>>(q, k, v, bias_base, ids, alpha, l, att);
    gemm_f32<false,true><<<g64, 256, 0, stream>>>(att, Wo + (size_t)l*DIM*DIM, bo + l*DIM, x, TOK, DIM, DIM);
    ln_kernel<<<TOK/4, 256, 0, stream>>>(x, g2 + l*DIM, be2 + l*DIM, x2);
    gemm_f32<true,false><<<gff, 256, 0, stream>>>(x2, W1 + (size_t)l*DIM*FFD, b1 + l*FFD, mid, TOK, FFD, DIM);
    gemm_f32<false,true><<<g64, 256, 0, stream>>>(mid, W2 + (size_t)l*FFD*DIM, b2 + l*DIM, x, TOK, DIM, FFD);
  }
  cls_kernel<<<8, 256, 0, stream>>>(x, gf, bf, Wc, bc, (float*)d_out);
}

// Round 2
// 335.521 us; speedup vs baseline: 3.4100x; 3.4100x over previous
//
#include <hip/hip_runtime.h>
#include <hip/hip_bf16.h>
#include <math.h>

#define TOK 8192       // B*S
#define DIM 256
#define SEQ 1024
#define NH 8
#define DHD 32
#define FFD 1024
#define NL 2
#define VOCAB 32000

typedef short bf16x8 __attribute__((ext_vector_type(8)));
typedef float f32x4 __attribute__((ext_vector_type(4)));

__device__ __forceinline__ ushort f2bf(float f) {
  union { float f; uint32_t u; } v; v.f = f;
  uint32_t r = v.u + 0x7FFFu + ((v.u >> 16) & 1u);
  return (ushort)(r >> 16);
}

// ---------------- embedding + ngram + tfidf bias ----------------
__global__ __launch_bounds__(256) void embed_kernel(
    const int* __restrict__ ids, const int* __restrict__ ngram_ids,
    const float* __restrict__ tfidf, const float* __restrict__ emb,
    const float* __restrict__ pos, const float* __restrict__ bucket,
    float* __restrict__ x, float* __restrict__ bias_base)
{
  __shared__ int ngs[12];
  const int t = blockIdx.x;
  const int id = ids[t];
  int idc = id; if (idc < 0) idc = 0; if (idc > VOCAB-1) idc = VOCAB-1;
  if (threadIdx.x < 12) ngs[threadIdx.x] = ngram_ids[idc*12 + threadIdx.x];
  if (threadIdx.x == 0) bias_base[t] = tfidf[idc];
  __syncthreads();
  const int d = threadIdx.x;
  const int s = t & (SEQ - 1);
  float v = emb[(size_t)id*DIM + d] + pos[s*DIM + d];
  float sum = 0.f; int cnt = 0;
  #pragma unroll
  for (int g = 0; g < 12; ++g) {
    const int ng = ngs[g];
    if (ng != 0) { sum += bucket[(size_t)ng*DIM + d]; cnt++; }
  }
  v += sum / fmaxf((float)cnt, 1.0f);
  x[(size_t)t*DIM + d] = v;
}

// ---------------- layernorm -> bf16: 1 wave per row, 4 rows/block ----------------
__global__ __launch_bounds__(256) void ln_bf16(
    const float* __restrict__ x, const float* __restrict__ g,
    const float* __restrict__ b, ushort* __restrict__ y)
{
  const int wave = threadIdx.x >> 6, lane = threadIdx.x & 63;
  const int row = blockIdx.x * 4 + wave;
  const float* xr = x + (size_t)row * DIM;
  float4 v = *reinterpret_cast<const float4*>(xr + lane*4);
  float s = v.x + v.y + v.z + v.w;
  #pragma unroll
  for (int o = 32; o >= 1; o >>= 1) s += __shfl_xor(s, o);
  const float mean = s * (1.f/256.f);
  const float dx0 = v.x-mean, dx1 = v.y-mean, dx2 = v.z-mean, dx3 = v.w-mean;
  float q = dx0*dx0 + dx1*dx1 + dx2*dx2 + dx3*dx3;
  #pragma unroll
  for (int o = 32; o >= 1; o >>= 1) q += __shfl_xor(q, o);
  const float rs = rsqrtf(q * (1.f/256.f) + 1e-5f);
  float4 gv = *reinterpret_cast<const float4*>(g + lane*4);
  float4 bv = *reinterpret_cast<const float4*>(b + lane*4);
  ushort4 o4;
  o4.x = f2bf(dx0*rs*gv.x + bv.x);
  o4.y = f2bf(dx1*rs*gv.y + bv.y);
  o4.z = f2bf(dx2*rs*gv.z + bv.z);
  o4.w = f2bf(dx3*rs*gv.w + bv.w);
  *reinterpret_cast<ushort4*>(y + (size_t)row*DIM + lane*4) = o4;
}

// ---------------- weight transpose + bf16 convert: src f32 [K][N] -> dst bf16 [N][K] ----------------
struct TDesc { const float* src; ushort* dst; int K; int N; };
struct TDescs { TDesc d[12]; };

__global__ __launch_bounds__(256) void transpose_conv(TDescs descs)
{
  const TDesc t = descs.d[blockIdx.z];
  const int k0 = blockIdx.x * 32, n0 = blockIdx.y * 32;
  if (k0 >= t.K || n0 >= t.N) return;
  __shared__ float tile[32][33];
  const int r = threadIdx.x >> 5, cc = threadIdx.x & 31;
  #pragma unroll
  for (int i = 0; i < 4; ++i)
    tile[r + i*8][cc] = t.src[(size_t)(k0 + r + i*8)*t.N + n0 + cc];
  __syncthreads();
  #pragma unroll
  for (int i = 0; i < 4; ++i)
    t.dst[(size_t)(n0 + r + i*8)*t.K + k0 + cc] = f2bf(tile[cc][r + i*8]);
}

// ---------------- bf16 MFMA GEMM: C[M,N] = A[M,K] @ B^T  (B given as [N][K]) ----------------
// 128x128 tile, BK=32, 4 waves each owning a 64x64 quadrant (4x4 frags of 16x16).
// MODE 0: bf16 out; MODE 1: bf16 out + relu; MODE 2: f32 accumulate (+=)
template<int KDIM, int NDIM, int MODE>
__global__ __launch_bounds__(256) void gemm_mfma(
    const ushort* __restrict__ A, const ushort* __restrict__ Bw,
    const float* __restrict__ bias0, const float* __restrict__ bias1,
    const float* __restrict__ bias2, void* __restrict__ Cout)
{
  __shared__ ushort Al[128*32];
  __shared__ ushort Bl[128*32];
  const int bm = blockIdx.y * 128, bn = blockIdx.x * 128;
  const int tid = threadIdx.x;
  const int w = tid >> 6, lane = tid & 63;
  const int wm = w >> 1, wn = w & 1;
  const int g = lane >> 4, c = lane & 15;
  const f32x4 fzero = {0.f, 0.f, 0.f, 0.f};
  f32x4 acc[4][4];
  #pragma unroll
  for (int m = 0; m < 4; ++m)
    #pragma unroll
    for (int n = 0; n < 4; ++n) acc[m][n] = fzero;

  for (int k0 = 0; k0 < KDIM; k0 += 32) {
    #pragma unroll
    for (int i = tid; i < 512; i += 256) {
      const int row = i >> 2, c8 = (i & 3) * 8;
      *(bf16x8*)&Al[i*8] = *(const bf16x8*)(A  + (size_t)(bm+row)*KDIM + k0 + c8);
      *(bf16x8*)&Bl[i*8] = *(const bf16x8*)(Bw + (size_t)(bn+row)*KDIM + k0 + c8);
    }
    __syncthreads();
    bf16x8 af[4], bfr[4];
    #pragma unroll
    for (int m = 0; m < 4; ++m)
      af[m] = *(const bf16x8*)&Al[(wm*64 + m*16 + c)*32 + g*8];
    #pragma unroll
    for (int n = 0; n < 4; ++n)
      bfr[n] = *(const bf16x8*)&Bl[(wn*64 + n*16 + c)*32 + g*8];
    #pragma unroll
    for (int m = 0; m < 4; ++m)
      #pragma unroll
      for (int n = 0; n < 4; ++n)
        acc[m][n] = __builtin_amdgcn_mfma_f32_16x16x32_bf16(af[m], bfr[n], acc[m][n], 0, 0, 0);
    __syncthreads();
  }
  // epilogue: C row = bm + wm*64 + m*16 + 4g + r, col = bn + wn*64 + n*16 + c
  #pragma unroll
  for (int m = 0; m < 4; ++m) {
    const int row0 = bm + wm*64 + m*16 + g*4;
    #pragma unroll
    for (int n = 0; n < 4; ++n) {
      const int col = bn + wn*64 + n*16 + c;
      float bb;
      if (NDIM == 768)
        bb = (col < 256) ? bias0[col] : (col < 512 ? bias1[col-256] : bias2[col-512]);
      else
        bb = bias0[col];
      #pragma unroll
      for (int r = 0; r < 4; ++r) {
        float vv = acc[m][n][r] + bb;
        if (MODE == 1) vv = fmaxf(vv, 0.f);
        if (MODE == 2) {
          float* C = (float*)Cout;
          C[(size_t)(row0 + r)*NDIM + col] += vv;
        } else {
          const float other = __shfl_xor(vv, 1);
          if ((c & 1) == 0) {
            const uint32_t word = (uint32_t)f2bf(vv) | ((uint32_t)f2bf(other) << 16);
            *(uint32_t*)((ushort*)Cout + (size_t)(row0 + r)*NDIM + col) = word;
          }
        }
      }
    }
  }
}

// ---------------- MFMA flash attention (bf16 inputs from fused qkv buffer) ----------------
// grid (SEQ/64, NH, B); block 256 = 4 waves; each wave owns 16 q-rows.
__global__ __launch_bounds__(256) void attn_mfma(
    const ushort* __restrict__ qkv, const float* __restrict__ bias_base,
    const int* __restrict__ ids, const float* __restrict__ alpha_arr, int l,
    ushort* __restrict__ O)
{
  const int qb = blockIdx.x * 64;
  const int h  = blockIdx.y;
  const int b  = blockIdx.z;
  const float alpha = alpha_arr[l];
  const float scale = 0.17677669529663687f;  // 1/sqrt(32)
  __shared__ ushort Kl[64*32];      // [key][d] bf16
  __shared__ ushort Vt[32*72];      // [d][key] bf16, padded stride 72
  __shared__ ushort Pl[4][16*72];   // per-wave P[q][key], padded stride 72
  __shared__ float bias_s[64];
  const int tid = threadIdx.x, w = tid >> 6, lane = tid & 63;
  const int g = lane >> 4, c = lane & 15;
  const f32x4 fzero = {0.f, 0.f, 0.f, 0.f};

  // Q fragment (hoisted): wave's rows qb + w*16 + (lane&15), d = g*8..g*8+7
  const bf16x8 qf = *(const bf16x8*)(qkv + (size_t)(b*SEQ + qb + w*16 + c)*768 + h*32 + g*8);

  f32x4 oacc[2]; oacc[0] = fzero; oacc[1] = fzero;
  float m_run[4], l_run[4];
  #pragma unroll
  for (int r = 0; r < 4; ++r) { m_run[r] = -1e30f; l_run[r] = 0.f; }

  for (int kt = 0; kt < SEQ; kt += 64) {
    // ---- stage K (row-major), V (transposed), bias ----
    {
      const int row = tid >> 2, c8 = (tid & 3) * 8;
      *(bf16x8*)&Kl[tid*8] =
        *(const bf16x8*)(qkv + (size_t)(b*SEQ + kt + row)*768 + 256 + h*32 + c8);
    }
    {
      const int d = tid & 31;
      const int k2 = ((tid >> 5)) * 2;
      #pragma unroll
      for (int j = 0; j < 4; ++j) {
        const int k = k2 + j*16;
        const ushort v0 = qkv[(size_t)(b*SEQ + kt + k    )*768 + 512 + h*32 + d];
        const ushort v1 = qkv[(size_t)(b*SEQ + kt + k + 1)*768 + 512 + h*32 + d];
        *(uint32_t*)&Vt[d*72 + k] = (uint32_t)v0 | ((uint32_t)v1 << 16);
      }
    }
    if (tid < 64) {
      const int spos = b*SEQ + kt + tid;
      bias_s[tid] = (ids[spos] == 0) ? -1e30f : bias_base[spos] * alpha;
    }
    __syncthreads();

    // ---- QK^T: scores for (q = 4g+r, key = ks*16 + c) ----
    f32x4 sf[4];
    #pragma unroll
    for (int ks = 0; ks < 4; ++ks) {
      const bf16x8 kfrag = *(const bf16x8*)&Kl[(ks*16 + c)*32 + g*8];
      sf[ks] = __builtin_amdgcn_mfma_f32_16x16x32_bf16(qf, kfrag, fzero, 0, 0, 0);
    }
    float p[4][4], mx[4];
    #pragma unroll
    for (int ks = 0; ks < 4; ++ks) {
      const float bb = bias_s[ks*16 + c];
      #pragma unroll
      for (int r = 0; r < 4; ++r) p[ks][r] = sf[ks][r]*scale + bb;
    }
    #pragma unroll
    for (int r = 0; r < 4; ++r)
      mx[r] = fmaxf(fmaxf(p[0][r], p[1][r]), fmaxf(p[2][r], p[3][r]));
    #pragma unroll
    for (int off = 1; off <= 8; off <<= 1)
      #pragma unroll
      for (int r = 0; r < 4; ++r)
        mx[r] = fmaxf(mx[r], __shfl_xor(mx[r], off));
    float sc_[4], lsum[4];
    #pragma unroll
    for (int r = 0; r < 4; ++r) {
      const float mn = fmaxf(m_run[r], mx[r]);
      sc_[r] = __expf(m_run[r] - mn);
      m_run[r] = mn;
      lsum[r] = 0.f;
    }
    #pragma unroll
    for (int ks = 0; ks < 4; ++ks)
      #pragma unroll
      for (int r = 0; r < 4; ++r) {
        const float e = __expf(p[ks][r] - m_run[r]);
        p[ks][r] = e;
        lsum[r] += e;
      }
    #pragma unroll
    for (int off = 1; off <= 8; off <<= 1)
      #pragma unroll
      for (int r = 0; r < 4; ++r)
        lsum[r] += __shfl_xor(lsum[r], off);
    #pragma unroll
    for (int r = 0; r < 4; ++r)
      l_run[r] = l_run[r]*sc_[r] + lsum[r];
    #pragma unroll
    for (int ds_ = 0; ds_ < 2; ++ds_)
      #pragma unroll
      for (int r = 0; r < 4; ++r)
        oacc[ds_][r] *= sc_[r];
    // ---- write P (bf16, even-lane packed pairs) ----
    #pragma unroll
    for (int ks = 0; ks < 4; ++ks)
      #pragma unroll
      for (int r = 0; r < 4; ++r) {
        const float mine = p[ks][r];
        const float other = __shfl_xor(mine, 1);
        if ((c & 1) == 0) {
          const uint32_t word = (uint32_t)f2bf(mine) | ((uint32_t)f2bf(other) << 16);
          *(uint32_t*)&Pl[w][(g*4 + r)*72 + ks*16 + c] = word;
        }
      }
    __syncthreads();   // P visible to all lanes of the wave (and block)

    // ---- PV: oacc[ds][q=4g+r][d = ds*16 + c] ----
    #pragma unroll
    for (int k2 = 0; k2 < 2; ++k2) {
      const bf16x8 pa = *(const bf16x8*)&Pl[w][c*72 + k2*32 + g*8];
      #pragma unroll
      for (int ds_ = 0; ds_ < 2; ++ds_) {
        const bf16x8 vb = *(const bf16x8*)&Vt[(ds_*16 + c)*72 + k2*32 + g*8];
        oacc[ds_] = __builtin_amdgcn_mfma_f32_16x16x32_bf16(pa, vb, oacc[ds_], 0, 0, 0);
      }
    }
    __syncthreads();   // before next tile overwrites Kl/Vt
  }
  // epilogue
  #pragma unroll
  for (int ds_ = 0; ds_ < 2; ++ds_)
    #pragma unroll
    for (int r = 0; r < 4; ++r) {
      const int row = qb + w*16 + g*4 + r;
      O[(size_t)(b*SEQ + row)*DIM + h*32 + ds_*16 + c] = f2bf(oacc[ds_][r] / l_run[r]);
    }
}

// ---------------- final LN (row 0 per batch) + classifier ----------------
__global__ __launch_bounds__(256) void cls_kernel(
    const float* __restrict__ x, const float* __restrict__ gf,
    const float* __restrict__ bf, const float* __restrict__ Wc,
    const float* __restrict__ bc, float* __restrict__ out)
{
  const int b = blockIdx.x;
  const int tid = threadIdx.x;
  const int wave = tid >> 6, lane = tid & 63;
  const float* xr = x + (size_t)b * SEQ * DIM;   // row (b, s=0)
  const float v = xr[tid];
  __shared__ float redm[4], redv[4], redc[4][4];
  float s = v;
  #pragma unroll
  for (int o = 32; o >= 1; o >>= 1) s += __shfl_xor(s, o);
  if (lane == 0) redm[wave] = s;
  __syncthreads();
  const float mean = (redm[0]+redm[1]+redm[2]+redm[3]) * (1.f/256.f);
  const float dv = v - mean;
  float q = dv * dv;
  #pragma unroll
  for (int o = 32; o >= 1; o >>= 1) q += __shfl_xor(q, o);
  if (lane == 0) redv[wave] = q;
  __syncthreads();
  const float var = (redv[0]+redv[1]+redv[2]+redv[3]) * (1.f/256.f);
  const float rs = rsqrtf(var + 1e-5f);
  const float yn = dv*rs*gf[tid] + bf[tid];
  float pc[4];
  #pragma unroll
  for (int cc = 0; cc < 4; ++cc) pc[cc] = yn * Wc[tid*4 + cc];
  #pragma unroll
  for (int cc = 0; cc < 4; ++cc) {
    #pragma unroll
    for (int o = 32; o >= 1; o >>= 1) pc[cc] += __shfl_xor(pc[cc], o);
  }
  if (lane == 0) {
    #pragma unroll
    for (int cc = 0; cc < 4; ++cc) redc[wave][cc] = pc[cc];
  }
  __syncthreads();
  if (tid < 4)
    out[b*4 + tid] = redc[0][tid] + redc[1][tid] + redc[2][tid] + redc[3][tid] + bc[tid];
}

extern "C" void kernel_launch(void* const* d_in, const int* in_sizes, int n_in,
                              void* d_out, int out_size, void* d_ws, size_t ws_size,
                              hipStream_t stream)
{
  const int*   ids    = (const int*)d_in[0];
  const int*   ngrams = (const int*)d_in[1];
  const float* tfidf  = (const float*)d_in[2];
  const float* emb    = (const float*)d_in[3];
  const float* pos    = (const float*)d_in[4];
  const float* bucket = (const float*)d_in[5];
  const float* Wq = (const float*)d_in[6];  const float* bq = (const float*)d_in[7];
  const float* Wk = (const float*)d_in[8];  const float* bk = (const float*)d_in[9];
  const float* Wv = (const float*)d_in[10]; const float* bv = (const float*)d_in[11];
  const float* Wo = (const float*)d_in[12]; const float* bo = (const float*)d_in[13];
  const float* g1 = (const float*)d_in[14]; const float* be1= (const float*)d_in[15];
  const float* g2 = (const float*)d_in[16]; const float* be2= (const float*)d_in[17];
  const float* W1 = (const float*)d_in[18]; const float* b1 = (const float*)d_in[19];
  const float* W2 = (const float*)d_in[20]; const float* b2 = (const float*)d_in[21];
  const float* alpha = (const float*)d_in[22];
  const float* gf = (const float*)d_in[23]; const float* bf = (const float*)d_in[24];
  const float* Wc = (const float*)d_in[25]; const float* bc = (const float*)d_in[26];

  uint8_t* base = (uint8_t*)d_ws;
  float*  x      = (float*)  base;                  //  8,388,608 B
  ushort* x2b    = (ushort*)(base + 8388608);       //  4,194,304 B
  ushort* qkvb   = (ushort*)(base + 12582912);      // 12,582,912 B
  ushort* attb   = (ushort*)(base + 25165824);      //  4,194,304 B
  ushort* midb   = (ushort*)(base + 29360128);      // 16,777,216 B
  float*  bias_b = (float*) (base + 46137344);      //     32,768 B
  ushort* WqkvT  = (ushort*)(base + 46170112);      //    786,432 B
  ushort* WoT    = (ushort*)(base + 46956544);      //    262,144 B
  ushort* W1T    = (ushort*)(base + 47218688);      //  1,048,576 B
  ushort* W2T    = (ushort*)(base + 48267264);      //  1,048,576 B  -> 49,315,840 total

  // weight transpose/convert descriptors
  TDescs td;
  for (int l = 0; l < NL; ++l) {
    td.d[6*l+0] = { Wq + (size_t)l*DIM*DIM, WqkvT + (size_t)l*768*DIM +   0*DIM, DIM, DIM };
    td.d[6*l+1] = { Wk + (size_t)l*DIM*DIM, WqkvT + (size_t)l*768*DIM + 256*DIM, DIM, DIM };
    td.d[6*l+2] = { Wv + (size_t)l*DIM*DIM, WqkvT + (size_t)l*768*DIM + 512*DIM, DIM, DIM };
    td.d[6*l+3] = { Wo + (size_t)l*DIM*DIM, WoT  + (size_t)l*DIM*DIM,  DIM, DIM };
    td.d[6*l+4] = { W1 + (size_t)l*DIM*FFD, W1T  + (size_t)l*FFD*DIM,  DIM, FFD };
    td.d[6*l+5] = { W2 + (size_t)l*FFD*DIM, W2T  + (size_t)l*DIM*FFD,  FFD, DIM };
  }
  transpose_conv<<<dim3(32, 32, 12), 256, 0, stream>>>(td);

  embed_kernel<<<TOK, 256, 0, stream>>>(ids, ngrams, tfidf, emb, pos, bucket, x, bias_b);

  const dim3 gqkv(6, TOK/128), gff1(8, TOK/128), g256(2, TOK/128);
  const dim3 ga(SEQ/64, NH, 8);
  for (int l = 0; l < NL; ++l) {
    ln_bf16<<<TOK/4, 256, 0, stream>>>(x, g1 + l*DIM, be1 + l*DIM, x2b);
    gemm_mfma<256, 768, 0><<<gqkv, 256, 0, stream>>>(
        x2b, WqkvT + (size_t)l*768*DIM, bq + l*DIM, bk + l*DIM, bv + l*DIM, qkvb);
    attn_mfma<<<ga, 256, 0, stream>>>(qkvb, bias_b, ids, alpha, l, attb);
    gemm_mfma<256, 256, 2><<<g256, 256, 0, stream>>>(
        attb, WoT + (size_t)l*DIM*DIM, bo + l*DIM, nullptr, nullptr, x);
    ln_bf16<<<TOK/4, 256, 0, stream>>>(x, g2 + l*DIM, be2 + l*DIM, x2b);
    gemm_mfma<256, 1024, 1><<<gff1, 256, 0, stream>>>(
        x2b, W1T + (size_t)l*FFD*DIM, b1 + l*FFD, nullptr, nullptr, midb);
    gemm_mfma<1024, 256, 2><<<g256, 256, 0, stream>>>(
        midb, W2T + (size_t)l*DIM*FFD, b2 + l*DIM, nullptr, nullptr, x);
  }
  cls_kernel<<<8, 256, 0, stream>>>(x, gf, bf, Wc, bc, (float*)d_out);
}

// Round 3
// 323.888 us; speedup vs baseline: 3.5324x; 1.0359x over previous
//
#include <hip/hip_runtime.h>
#include <hip/hip_bf16.h>
#include <math.h>

#define TOK 8192       // B*S
#define DIM 256
#define SEQ 1024
#define NH 8
#define FFD 1024
#define NL 2
#define VOCAB 32000

typedef short bf16x8 __attribute__((ext_vector_type(8)));
typedef float f32x4 __attribute__((ext_vector_type(4)));

__device__ __forceinline__ ushort f2bf(float f) {
  union { float f; uint32_t u; } v; v.f = f;
  uint32_t r = v.u + 0x7FFFu + ((v.u >> 16) & 1u);
  return (ushort)(r >> 16);
}

__device__ __forceinline__ void gload_lds16(const ushort* gp, ushort* lp) {
  __builtin_amdgcn_global_load_lds(
      (const __attribute__((address_space(1))) void*)gp,
      (__attribute__((address_space(3))) void*)lp, 16, 0, 0);
}

// ---------------- embedding + ngram + masked tfidf bias ----------------
__global__ __launch_bounds__(256) void embed_kernel(
    const int* __restrict__ ids, const int* __restrict__ ngram_ids,
    const float* __restrict__ tfidf, const float* __restrict__ emb,
    const float* __restrict__ pos, const float* __restrict__ bucket,
    float* __restrict__ x, float* __restrict__ bm)
{
  __shared__ int ngs[12];
  const int t = blockIdx.x;
  const int id = ids[t];
  int idc = id; if (idc < 0) idc = 0; if (idc > VOCAB-1) idc = VOCAB-1;
  if (threadIdx.x < 12) ngs[threadIdx.x] = ngram_ids[idc*12 + threadIdx.x];
  if (threadIdx.x == 0) bm[t] = (id == 0) ? -1e30f : tfidf[idc];
  __syncthreads();
  const int d = threadIdx.x;
  const int s = t & (SEQ - 1);
  float v = emb[(size_t)id*DIM + d] + pos[s*DIM + d];
  float sum = 0.f; int cnt = 0;
  #pragma unroll
  for (int g = 0; g < 12; ++g) {
    const int ng = ngs[g];
    if (ng != 0) { sum += bucket[(size_t)ng*DIM + d]; cnt++; }
  }
  v += sum / fmaxf((float)cnt, 1.0f);
  x[(size_t)t*DIM + d] = v;
}

// ---------------- layernorm -> bf16 ----------------
__global__ __launch_bounds__(256) void ln_bf16(
    const float* __restrict__ x, const float* __restrict__ g,
    const float* __restrict__ b, ushort* __restrict__ y)
{
  const int wave = threadIdx.x >> 6, lane = threadIdx.x & 63;
  const int row = blockIdx.x * 4 + wave;
  const float* xr = x + (size_t)row * DIM;
  float4 v = *reinterpret_cast<const float4*>(xr + lane*4);
  float s = v.x + v.y + v.z + v.w;
  #pragma unroll
  for (int o = 32; o >= 1; o >>= 1) s += __shfl_xor(s, o);
  const float mean = s * (1.f/256.f);
  const float dx0 = v.x-mean, dx1 = v.y-mean, dx2 = v.z-mean, dx3 = v.w-mean;
  float q = dx0*dx0 + dx1*dx1 + dx2*dx2 + dx3*dx3;
  #pragma unroll
  for (int o = 32; o >= 1; o >>= 1) q += __shfl_xor(q, o);
  const float rs = rsqrtf(q * (1.f/256.f) + 1e-5f);
  float4 gv = *reinterpret_cast<const float4*>(g + lane*4);
  float4 bv = *reinterpret_cast<const float4*>(b + lane*4);
  ushort4 o4;
  o4.x = f2bf(dx0*rs*gv.x + bv.x);
  o4.y = f2bf(dx1*rs*gv.y + bv.y);
  o4.z = f2bf(dx2*rs*gv.z + bv.z);
  o4.w = f2bf(dx3*rs*gv.w + bv.w);
  *reinterpret_cast<ushort4*>(y + (size_t)row*DIM + lane*4) = o4;
}

// ---------------- weight transpose + bf16: f32 [K][N] -> bf16 [N][K] ----------------
struct TDesc { const float* src; ushort* dst; int K; int N; };
struct TDescs { TDesc d[12]; };

__global__ __launch_bounds__(256) void transpose_conv(TDescs descs)
{
  const TDesc t = descs.d[blockIdx.z];
  const int k0 = blockIdx.x * 32, n0 = blockIdx.y * 32;
  if (k0 >= t.K || n0 >= t.N) return;
  __shared__ float tile[32][33];
  const int r = threadIdx.x >> 5, cc = threadIdx.x & 31;
  #pragma unroll
  for (int i = 0; i < 4; ++i)
    tile[r + i*8][cc] = t.src[(size_t)(k0 + r + i*8)*t.N + n0 + cc];
  __syncthreads();
  #pragma unroll
  for (int i = 0; i < 4; ++i)
    t.dst[(size_t)(n0 + r + i*8)*t.K + k0 + cc] = f2bf(tile[cc][r + i*8]);
}

// ---------------- bf16 MFMA GEMM: C[M,N] = A[M,K] @ B^T  (B as [N][K]) ----------------
// BM=64, BN=128, BK=32; 4 waves, wave w owns cols [w*32, w*32+32); frags 4x2.
// global_load_lds staging, double-buffered, 2-phase pipeline.
// MODE 1: relu + bf16 out (stride NDIM); MODE 2: f32 += (stride NDIM);
// MODE 3: qkv -> Q,K bf16 into Cout stride 512; V transposed into vtb[b][h][d][s].
template<int KDIM, int NDIM, int MODE>
__global__ __launch_bounds__(256) void gemm_mfma(
    const ushort* __restrict__ A, const ushort* __restrict__ Bw,
    const float* __restrict__ bias0, const float* __restrict__ bias1,
    const float* __restrict__ bias2, void* __restrict__ Cout,
    ushort* __restrict__ vtb)
{
  __shared__ ushort Al[2][64*32];
  __shared__ ushort Bl[2][128*32];
  const int bm = blockIdx.y * 64, bn = blockIdx.x * 128;
  const int tid = threadIdx.x, w = tid >> 6, lane = tid & 63;
  const int g = lane >> 4, c = lane & 15;
  const int lrow = lane >> 2, lc8 = (lane & 3) * 8;
  const f32x4 fzero = {0.f, 0.f, 0.f, 0.f};
  f32x4 acc[4][2];
  #pragma unroll
  for (int m = 0; m < 4; ++m) { acc[m][0] = fzero; acc[m][1] = fzero; }

#define STAGE(buf, k0)                                                         \
  {                                                                            \
    _Pragma("unroll")                                                          \
    for (int ch = w; ch < 12; ch += 4) {                                       \
      if (ch < 4)                                                              \
        gload_lds16(A + (size_t)(bm + ch*16 + lrow)*KDIM + (k0) + lc8,         \
                    &Al[buf][ch*512]);                                         \
      else                                                                     \
        gload_lds16(Bw + (size_t)(bn + (ch-4)*16 + lrow)*KDIM + (k0) + lc8,    \
                    &Bl[buf][(ch-4)*512]);                                     \
    }                                                                          \
  }

  STAGE(0, 0);
  asm volatile("s_waitcnt vmcnt(0)");
  __syncthreads();
  int buf = 0;
  for (int k0 = 0; k0 < KDIM; k0 += 32) {
    if (k0 + 32 < KDIM) STAGE(buf^1, k0 + 32);
    bf16x8 af[4], bfr[2];
    #pragma unroll
    for (int m = 0; m < 4; ++m)
      af[m] = *(const bf16x8*)&Al[buf][(m*16 + c)*32 + g*8];
    #pragma unroll
    for (int n = 0; n < 2; ++n)
      bfr[n] = *(const bf16x8*)&Bl[buf][(w*32 + n*16 + c)*32 + g*8];
    #pragma unroll
    for (int m = 0; m < 4; ++m)
      #pragma unroll
      for (int n = 0; n < 2; ++n)
        acc[m][n] = __builtin_amdgcn_mfma_f32_16x16x32_bf16(af[m], bfr[n], acc[m][n], 0, 0, 0);
    asm volatile("s_waitcnt vmcnt(0)");
    __syncthreads();
    buf ^= 1;
  }
#undef STAGE

  #pragma unroll
  for (int m = 0; m < 4; ++m) {
    const int row0 = bm + m*16 + g*4;
    #pragma unroll
    for (int n = 0; n < 2; ++n) {
      const int col = bn + w*32 + n*16 + c;
      if (MODE == 2) {
        float* C = (float*)Cout;
        const float bb = bias0[col];
        #pragma unroll
        for (int r = 0; r < 4; ++r)
          C[(size_t)(row0 + r)*NDIM + col] += acc[m][n][r] + bb;
      } else if (MODE == 1) {
        const float bb = bias0[col];
        #pragma unroll
        for (int r = 0; r < 4; ++r) {
          const float vv = fmaxf(acc[m][n][r] + bb, 0.f);
          const float other = __shfl_xor(vv, 1);
          if ((c & 1) == 0) {
            const uint32_t word = (uint32_t)f2bf(vv) | ((uint32_t)f2bf(other) << 16);
            *(uint32_t*)((ushort*)Cout + (size_t)(row0 + r)*NDIM + col) = word;
          }
        }
      } else {  // MODE 3
        if (col < 512) {
          const float bb = (col < 256) ? bias0[col] : bias1[col - 256];
          #pragma unroll
          for (int r = 0; r < 4; ++r) {
            const float vv = acc[m][n][r] + bb;
            const float other = __shfl_xor(vv, 1);
            if ((c & 1) == 0) {
              const uint32_t word = (uint32_t)f2bf(vv) | ((uint32_t)f2bf(other) << 16);
              *(uint32_t*)((ushort*)Cout + (size_t)(row0 + r)*512 + col) = word;
            }
          }
        } else {
          const int hd = col - 512;
          const int hh = hd >> 5, d = hd & 31;
          const float bb = bias2[hd];
          const int b_ = row0 >> 10, s = row0 & (SEQ - 1);
          ushort4 w4;
          w4.x = f2bf(acc[m][n][0] + bb);
          w4.y = f2bf(acc[m][n][1] + bb);
          w4.z = f2bf(acc[m][n][2] + bb);
          w4.w = f2bf(acc[m][n][3] + bb);
          *(ushort4*)(vtb + ((size_t)((b_*NH + hh)*32 + d) << 10) + s) = w4;
        }
      }
    }
  }
}

// ---------------- barrier-free MFMA flash attention ----------------
// grid (SEQ/64, NH, B); 4 waves, each owns 16 q-rows; K/V frags direct from global.
__global__ __launch_bounds__(256) void attn_mfma(
    const ushort* __restrict__ qk, const ushort* __restrict__ vt,
    const float* __restrict__ bm, const float* __restrict__ alpha_arr, int l,
    ushort* __restrict__ O)
{
  const int qb = blockIdx.x * 64;
  const int h  = blockIdx.y;
  const int b  = blockIdx.z;
  const float alpha = alpha_arr[l];
  const float scale = 0.17677669529663687f;  // 1/sqrt(32)
  __shared__ ushort Pl[4][16*72];
  const int tid = threadIdx.x, w = tid >> 6, lane = tid & 63;
  const int g = lane >> 4, c = lane & 15;
  const f32x4 fzero = {0.f, 0.f, 0.f, 0.f};

  const bf16x8 qf = *(const bf16x8*)(qk + (size_t)(b*SEQ + qb + w*16 + c)*512 + h*32 + g*8);
  const ushort* kbase = qk + (size_t)b*SEQ*512 + 256 + h*32 + g*8;
  const ushort* vbase = vt + ((size_t)(b*NH + h)*32)*SEQ + g*8;
  const float*  bmb   = bm + b*SEQ;

  f32x4 oacc[2]; oacc[0] = fzero; oacc[1] = fzero;
  float m_run[4], l_run[4];
  #pragma unroll
  for (int r = 0; r < 4; ++r) { m_run[r] = -1e30f; l_run[r] = 0.f; }

  bf16x8 kfA[4], vfA[4], kfB[4], vfB[4];
  float bmA[4], bmB[4];

#define LOADT(kt, kf, vf, bv)                                                  \
  {                                                                            \
    _Pragma("unroll")                                                          \
    for (int ks = 0; ks < 4; ++ks) {                                           \
      kf[ks] = *(const bf16x8*)(kbase + (size_t)((kt) + ks*16 + c)*512);       \
      bv[ks] = bmb[(kt) + ks*16 + c];                                          \
    }                                                                          \
    _Pragma("unroll")                                                          \
    for (int j = 0; j < 4; ++j)                                                \
      vf[j] = *(const bf16x8*)(vbase + (size_t)((j>>1)*16 + c)*SEQ + (kt) + (j&1)*32); \
  }

#define ATILE(kf, vf, bv)                                                      \
  {                                                                            \
    f32x4 sf[4];                                                               \
    _Pragma("unroll")                                                          \
    for (int ks = 0; ks < 4; ++ks)                                             \
      sf[ks] = __builtin_amdgcn_mfma_f32_16x16x32_bf16(qf, kf[ks], fzero, 0, 0, 0); \
    float p[4][4], mx[4];                                                      \
    _Pragma("unroll")                                                          \
    for (int ks = 0; ks < 4; ++ks) {                                           \
      const float bb = bv[ks] * alpha;                                         \
      _Pragma("unroll")                                                        \
      for (int r = 0; r < 4; ++r) p[ks][r] = sf[ks][r]*scale + bb;             \
    }                                                                          \
    _Pragma("unroll")                                                          \
    for (int r = 0; r < 4; ++r)                                                \
      mx[r] = fmaxf(fmaxf(p[0][r], p[1][r]), fmaxf(p[2][r], p[3][r]));         \
    _Pragma("unroll")                                                          \
    for (int off = 1; off <= 8; off <<= 1)                                     \
      _Pragma("unroll")                                                        \
      for (int r = 0; r < 4; ++r)                                              \
        mx[r] = fmaxf(mx[r], __shfl_xor(mx[r], off));                          \
    float sc_[4], lsum[4];                                                     \
    _Pragma("unroll")                                                          \
    for (int r = 0; r < 4; ++r) {                                              \
      const float mn = fmaxf(m_run[r], mx[r]);                                 \
      sc_[r] = __expf(m_run[r] - mn);                                          \
      m_run[r] = mn; lsum[r] = 0.f;                                            \
    }                                                                          \
    _Pragma("unroll")                                                          \
    for (int ks = 0; ks < 4; ++ks)                                             \
      _Pragma("unroll")                                                        \
      for (int r = 0; r < 4; ++r) {                                            \
        const float e = __expf(p[ks][r] - m_run[r]);                           \
        p[ks][r] = e; lsum[r] += e;                                            \
      }                                                                        \
    _Pragma("unroll")                                                          \
    for (int off = 1; off <= 8; off <<= 1)                                     \
      _Pragma("unroll")                                                        \
      for (int r = 0; r < 4; ++r) lsum[r] += __shfl_xor(lsum[r], off);         \
    _Pragma("unroll")                                                          \
    for (int r = 0; r < 4; ++r) l_run[r] = l_run[r]*sc_[r] + lsum[r];          \
    _Pragma("unroll")                                                          \
    for (int ds_ = 0; ds_ < 2; ++ds_)                                          \
      _Pragma("unroll")                                                        \
      for (int r = 0; r < 4; ++r) oacc[ds_][r] *= sc_[r];                      \
    _Pragma("unroll")                                                          \
    for (int ks = 0; ks < 4; ++ks)                                             \
      _Pragma("unroll")                                                        \
      for (int r = 0; r < 4; ++r) {                                            \
        const float mine = p[ks][r];                                           \
        const float other = __shfl_xor(mine, 1);                               \
        if ((c & 1) == 0) {                                                    \
          const uint32_t word = (uint32_t)f2bf(mine) | ((uint32_t)f2bf(other) << 16); \
          *(uint32_t*)&Pl[w][(g*4 + r)*72 + ks*16 + c] = word;                 \
        }                                                                      \
      }                                                                        \
    asm volatile("s_waitcnt lgkmcnt(0)" ::: "memory");                         \
    __builtin_amdgcn_sched_barrier(0);                                         \
    _Pragma("unroll")                                                          \
    for (int k2 = 0; k2 < 2; ++k2) {                                           \
      const bf16x8 pa = *(const bf16x8*)&Pl[w][c*72 + k2*32 + g*8];            \
      _Pragma("unroll")                                                        \
      for (int ds_ = 0; ds_ < 2; ++ds_)                                        \
        oacc[ds_] = __builtin_amdgcn_mfma_f32_16x16x32_bf16(pa, vf[ds_*2 + k2], oacc[ds_], 0, 0, 0); \
    }                                                                          \
  }

  LOADT(0, kfA, vfA, bmA);
  for (int kt = 0; kt < SEQ; kt += 128) {
    LOADT(kt + 64, kfB, vfB, bmB);
    ATILE(kfA, vfA, bmA);
    if (kt + 128 < SEQ) LOADT(kt + 128, kfA, vfA, bmA);
    ATILE(kfB, vfB, bmB);
  }
#undef LOADT
#undef ATILE

  #pragma unroll
  for (int ds_ = 0; ds_ < 2; ++ds_)
    #pragma unroll
    for (int r = 0; r < 4; ++r) {
      const int row = qb + w*16 + g*4 + r;
      O[(size_t)(b*SEQ + row)*DIM + h*32 + ds_*16 + c] = f2bf(oacc[ds_][r] / l_run[r]);
    }
}

// ---------------- final LN (row 0 per batch) + classifier ----------------
__global__ __launch_bounds__(256) void cls_kernel(
    const float* __restrict__ x, const float* __restrict__ gf,
    const float* __restrict__ bf, const float* __restrict__ Wc,
    const float* __restrict__ bc, float* __restrict__ out)
{
  const int b = blockIdx.x;
  const int tid = threadIdx.x;
  const int wave = tid >> 6, lane = tid & 63;
  const float* xr = x + (size_t)b * SEQ * DIM;
  const float v = xr[tid];
  __shared__ float redm[4], redv[4], redc[4][4];
  float s = v;
  #pragma unroll
  for (int o = 32; o >= 1; o >>= 1) s += __shfl_xor(s, o);
  if (lane == 0) redm[wave] = s;
  __syncthreads();
  const float mean = (redm[0]+redm[1]+redm[2]+redm[3]) * (1.f/256.f);
  const float dv = v - mean;
  float q = dv * dv;
  #pragma unroll
  for (int o = 32; o >= 1; o >>= 1) q += __shfl_xor(q, o);
  if (lane == 0) redv[wave] = q;
  __syncthreads();
  const float var = (redv[0]+redv[1]+redv[2]+redv[3]) * (1.f/256.f);
  const float rs = rsqrtf(var + 1e-5f);
  const float yn = dv*rs*gf[tid] + bf[tid];
  float pc[4];
  #pragma unroll
  for (int cc = 0; cc < 4; ++cc) pc[cc] = yn * Wc[tid*4 + cc];
  #pragma unroll
  for (int cc = 0; cc < 4; ++cc) {
    #pragma unroll
    for (int o = 32; o >= 1; o >>= 1) pc[cc] += __shfl_xor(pc[cc], o);
  }
  if (lane == 0) {
    #pragma unroll
    for (int cc = 0; cc < 4; ++cc) redc[wave][cc] = pc[cc];
  }
  __syncthreads();
  if (tid < 4)
    out[b*4 + tid] = redc[0][tid] + redc[1][tid] + redc[2][tid] + redc[3][tid] + bc[tid];
}

extern "C" void kernel_launch(void* const* d_in, const int* in_sizes, int n_in,
                              void* d_out, int out_size, void* d_ws, size_t ws_size,
                              hipStream_t stream)
{
  const int*   ids    = (const int*)d_in[0];
  const int*   ngrams = (const int*)d_in[1];
  const float* tfidf  = (const float*)d_in[2];
  const float* emb    = (const float*)d_in[3];
  const float* pos    = (const float*)d_in[4];
  const float* bucket = (const float*)d_in[5];
  const float* Wq = (const float*)d_in[6];  const float* bq = (const float*)d_in[7];
  const float* Wk = (const float*)d_in[8];  const float* bk = (const float*)d_in[9];
  const float* Wv = (const float*)d_in[10]; const float* bv = (const float*)d_in[11];
  const float* Wo = (const float*)d_in[12]; const float* bo = (const float*)d_in[13];
  const float* g1 = (const float*)d_in[14]; const float* be1= (const float*)d_in[15];
  const float* g2 = (const float*)d_in[16]; const float* be2= (const float*)d_in[17];
  const float* W1 = (const float*)d_in[18]; const float* b1 = (const float*)d_in[19];
  const float* W2 = (const float*)d_in[20]; const float* b2 = (const float*)d_in[21];
  const float* alpha = (const float*)d_in[22];
  const float* gf = (const float*)d_in[23]; const float* bf = (const float*)d_in[24];
  const float* Wc = (const float*)d_in[25]; const float* bc = (const float*)d_in[26];

  uint8_t* base = (uint8_t*)d_ws;
  float*  x      = (float*)  base;                  //  8,388,608
  ushort* x2b    = (ushort*)(base + 8388608);       //  4,194,304
  ushort* qkb    = (ushort*)(base + 12582912);      //  8,388,608
  ushort* vtb    = (ushort*)(base + 20971520);      //  4,194,304
  ushort* attb   = (ushort*)(base + 25165824);      //  4,194,304
  ushort* midb   = (ushort*)(base + 29360128);      // 16,777,216
  float*  bmb    = (float*) (base + 46137344);      //     32,768
  ushort* WqkvT  = (ushort*)(base + 46170112);      //    786,432
  ushort* WoT    = (ushort*)(base + 46956544);      //    262,144
  ushort* W1T    = (ushort*)(base + 47218688);      //  1,048,576
  ushort* W2T    = (ushort*)(base + 48267264);      //  1,048,576

  TDescs td;
  for (int l = 0; l < NL; ++l) {
    td.d[6*l+0] = { Wq + (size_t)l*DIM*DIM, WqkvT + (size_t)l*768*DIM +   0*DIM, DIM, DIM };
    td.d[6*l+1] = { Wk + (size_t)l*DIM*DIM, WqkvT + (size_t)l*768*DIM + 256*DIM, DIM, DIM };
    td.d[6*l+2] = { Wv + (size_t)l*DIM*DIM, WqkvT + (size_t)l*768*DIM + 512*DIM, DIM, DIM };
    td.d[6*l+3] = { Wo + (size_t)l*DIM*DIM, WoT  + (size_t)l*DIM*DIM,  DIM, DIM };
    td.d[6*l+4] = { W1 + (size_t)l*DIM*FFD, W1T  + (size_t)l*FFD*DIM,  DIM, FFD };
    td.d[6*l+5] = { W2 + (size_t)l*FFD*DIM, W2T  + (size_t)l*DIM*FFD,  FFD, DIM };
  }
  transpose_conv<<<dim3(32, 32, 12), 256, 0, stream>>>(td);

  embed_kernel<<<TOK, 256, 0, stream>>>(ids, ngrams, tfidf, emb, pos, bucket, x, bmb);

  const dim3 gqkv(6, TOK/64), gff1(8, TOK/64), g256(2, TOK/64);
  const dim3 ga(SEQ/64, NH, 8);
  for (int l = 0; l < NL; ++l) {
    ln_bf16<<<TOK/4, 256, 0, stream>>>(x, g1 + l*DIM, be1 + l*DIM, x2b);
    gemm_mfma<256, 768, 3><<<gqkv, 256, 0, stream>>>(
        x2b, WqkvT + (size_t)l*768*DIM, bq + l*DIM, bk + l*DIM, bv + l*DIM, qkb, vtb);
    attn_mfma<<<ga, 256, 0, stream>>>(qkb, vtb, bmb, alpha, l, attb);
    gemm_mfma<256, 256, 2><<<g256, 256, 0, stream>>>(
        attb, WoT + (size_t)l*DIM*DIM, bo + l*DIM, nullptr, nullptr, x, nullptr);
    ln_bf16<<<TOK/4, 256, 0, stream>>>(x, g2 + l*DIM, be2 + l*DIM, x2b);
    gemm_mfma<256, 1024, 1><<<gff1, 256, 0, stream>>>(
        x2b, W1T + (size_t)l*FFD*DIM, b1 + l*FFD, nullptr, nullptr, midb, nullptr);
    gemm_mfma<1024, 256, 2><<<g256, 256, 0, stream>>>(
        midb, W2T + (size_t)l*DIM*FFD, b2 + l*DIM, nullptr, nullptr, x, nullptr);
  }
  cls_kernel<<<8, 256, 0, stream>>>(x, gf, bf, Wc, bc, (float*)d_out);
}